// Round 1
// baseline (7744.093 us; speedup 1.0000x reference)
//
#include <hip/hip_runtime.h>

// PropLayer: 3 weighted segment-sums + passthrough.
// out layout (floats): [paper 300000*256][author 150000*256][venue 10000*256]

__global__ __launch_bounds__(256) void edge_scatter_kernel(
    const float* __restrict__ src_h,     // source node features, D=256
    const int*   __restrict__ src_idx,   // [E]
    const int*   __restrict__ dst_idx,   // [E]
    const float* __restrict__ w0,        // [E]
    const float* __restrict__ w1,        // [E] or nullptr
    float*       __restrict__ out,       // destination accumulator
    int n_edges)
{
    int tid  = blockIdx.x * blockDim.x + threadIdx.x;
    int e    = tid >> 6;          // one 64-lane wave per edge
    if (e >= n_edges) return;
    int lane = tid & 63;

    float w = w0[e];
    if (w1) w *= w1[e];

    const float4 v = *(reinterpret_cast<const float4*>(
                         src_h + (size_t)src_idx[e] * 256) + lane);

    float* dst = out + (size_t)dst_idx[e] * 256 + lane * 4;
    unsafeAtomicAdd(dst + 0, v.x * w);
    unsafeAtomicAdd(dst + 1, v.y * w);
    unsafeAtomicAdd(dst + 2, v.z * w);
    unsafeAtomicAdd(dst + 3, v.w * w);
}

extern "C" void kernel_launch(void* const* d_in, const int* in_sizes, int n_in,
                              void* d_out, int out_size, void* d_ws, size_t ws_size,
                              hipStream_t stream)
{
    const float* paper_h  = (const float*)d_in[0];
    const float* author_h = (const float*)d_in[1];
    const int*   wb_src   = (const int*)d_in[2];
    const int*   wb_dst   = (const int*)d_in[3];
    const float* wb_w     = (const float*)d_in[4];
    const int*   pi_src   = (const int*)d_in[5];
    const int*   pi_dst   = (const int*)d_in[6];
    const float* pi_alpha = (const float*)d_in[7];
    const float* pi_w     = (const float*)d_in[8];
    const int*   hp_src   = (const int*)d_in[9];
    const int*   hp_dst   = (const int*)d_in[10];
    const float* hp_feat  = (const float*)d_in[11];
    const float* hp_alpha = (const float*)d_in[12];

    const int D = 256;
    const int n_paper  = in_sizes[0] / D;
    const int n_author = in_sizes[1] / D;
    const int E_wb = in_sizes[2];
    const int E_pi = in_sizes[5];
    const int E_hp = in_sizes[9];

    float* out        = (float*)d_out;
    float* out_paper  = out;
    float* out_author = out + (size_t)n_paper * D;
    float* out_venue  = out_author + (size_t)n_author * D;
    const size_t n_accum_floats = (size_t)out_size - (size_t)n_paper * D; // author+venue

    // 1) passthrough: paper_h -> out0
    hipMemcpyAsync(out_paper, paper_h, (size_t)n_paper * D * sizeof(float),
                   hipMemcpyDeviceToDevice, stream);

    // 2) zero the accumulated regions (harness poisons once, never re-poisons)
    hipMemsetAsync(out_author, 0, n_accum_floats * sizeof(float), stream);

    // 3) edge scatters: one wave per edge
    auto launch = [&](const float* src_h, const int* si, const int* di,
                      const float* w0, const float* w1, float* dst, int E) {
        if (E <= 0) return;
        int blocks = (E + 3) / 4;               // 4 edges per 256-thread block
        edge_scatter_kernel<<<blocks, 256, 0, stream>>>(src_h, si, di, w0, w1, dst, E);
    };

    launch(paper_h,  wb_src, wb_dst, wb_w,     nullptr,  out_author, E_wb);
    launch(paper_h,  pi_src, pi_dst, pi_alpha, pi_w,     out_venue,  E_pi);
    launch(author_h, hp_src, hp_dst, hp_feat,  hp_alpha, out_venue,  E_hp);
}

// Round 2
// 1046.139 us; speedup vs baseline: 7.4025x; 7.4025x over previous
//
#include <hip/hip_runtime.h>

// PropLayer: 3 weighted segment-sums + passthrough, CSR-gather formulation.
// out layout (floats): [paper N_P*256][author N_A*256][venue N_V*256]

// ---------------- CSR build ----------------

__global__ __launch_bounds__(256) void hist_kernel(const int* __restrict__ dst, int E,
                                                   int* __restrict__ counts) {
    int e = blockIdx.x * blockDim.x + threadIdx.x;
    if (e < E) atomicAdd(&counts[dst[e]], 1);
}

__global__ __launch_bounds__(256) void scan_block_sums(const int* __restrict__ counts, int n,
                                                       int* __restrict__ partials) {
    __shared__ int s[256];
    int i = blockIdx.x * 256 + threadIdx.x;
    s[threadIdx.x] = (i < n) ? counts[i] : 0;
    __syncthreads();
    for (int st = 128; st > 0; st >>= 1) {
        if (threadIdx.x < st) s[threadIdx.x] += s[threadIdx.x + st];
        __syncthreads();
    }
    if (threadIdx.x == 0) partials[blockIdx.x] = s[0];
}

__global__ void scan_partials_serial(int* partials, int m) {
    if (blockIdx.x == 0 && threadIdx.x == 0) {
        int acc = 0;
        for (int i = 0; i < m; ++i) { int v = partials[i]; partials[i] = acc; acc += v; }
    }
}

__global__ __launch_bounds__(256) void scan_write_offs(const int* __restrict__ counts, int n,
                                                       const int* __restrict__ partials,
                                                       int* __restrict__ offs) {
    __shared__ int s[256];
    int i = blockIdx.x * 256 + threadIdx.x;
    int v = (i < n) ? counts[i] : 0;
    s[threadIdx.x] = v;
    __syncthreads();
    for (int st = 1; st < 256; st <<= 1) {
        int t = (threadIdx.x >= st) ? s[threadIdx.x - st] : 0;
        __syncthreads();
        s[threadIdx.x] += t;
        __syncthreads();
    }
    int incl = s[threadIdx.x];
    if (i < n) offs[i] = partials[blockIdx.x] + (incl - v);
    if (i == n - 1) offs[n] = partials[blockIdx.x] + incl;
}

__global__ __launch_bounds__(256) void fill_csr(const int* __restrict__ dst, int E,
                                                const int* __restrict__ offs,
                                                int* __restrict__ cursor,
                                                int* __restrict__ eids) {
    int e = blockIdx.x * blockDim.x + threadIdx.x;
    if (e >= E) return;
    int d = dst[e];
    int pos = offs[d] + atomicAdd(&cursor[d], 1);
    eids[pos] = e;
}

// ---------------- gathers: one 64-lane wave per destination row ----------------

__global__ __launch_bounds__(256) void gather_author_kernel(
    const float* __restrict__ paper_h,
    const int* __restrict__ src_idx, const float* __restrict__ w,
    const int* __restrict__ offs, const int* __restrict__ eids,
    float* __restrict__ out, int n_rows)
{
    int tid = blockIdx.x * blockDim.x + threadIdx.x;
    int row = tid >> 6, lane = tid & 63;
    if (row >= n_rows) return;
    int beg = offs[row], end = offs[row + 1];
    float ax = 0.f, ay = 0.f, az = 0.f, aw = 0.f;
    for (int p = beg; p < end; ++p) {
        int e = eids[p];
        float wt = w[e];
        float4 v = *(reinterpret_cast<const float4*>(
                       paper_h + (size_t)src_idx[e] * 256) + lane);
        ax += v.x * wt; ay += v.y * wt; az += v.z * wt; aw += v.w * wt;
    }
    float4 o = {ax, ay, az, aw};
    *(reinterpret_cast<float4*>(out + (size_t)row * 256) + lane) = o;
}

__global__ __launch_bounds__(256) void gather_venue_kernel(
    const float* __restrict__ paper_h,  const int* __restrict__ pi_src,
    const float* __restrict__ pi_alpha, const float* __restrict__ pi_w,
    const int* __restrict__ pi_offs,    const int* __restrict__ pi_eids,
    const float* __restrict__ author_h, const int* __restrict__ hp_src,
    const float* __restrict__ hp_feat,  const float* __restrict__ hp_alpha,
    const int* __restrict__ hp_offs,    const int* __restrict__ hp_eids,
    float* __restrict__ out, int n_rows)
{
    int tid = blockIdx.x * blockDim.x + threadIdx.x;
    int row = tid >> 6, lane = tid & 63;
    if (row >= n_rows) return;
    float ax = 0.f, ay = 0.f, az = 0.f, aw = 0.f;
    {
        int beg = pi_offs[row], end = pi_offs[row + 1];
        for (int p = beg; p < end; ++p) {
            int e = pi_eids[p];
            float wt = pi_alpha[e] * pi_w[e];
            float4 v = *(reinterpret_cast<const float4*>(
                           paper_h + (size_t)pi_src[e] * 256) + lane);
            ax += v.x * wt; ay += v.y * wt; az += v.z * wt; aw += v.w * wt;
        }
    }
    {
        int beg = hp_offs[row], end = hp_offs[row + 1];
        for (int p = beg; p < end; ++p) {
            int e = hp_eids[p];
            float wt = hp_feat[e] * hp_alpha[e];
            float4 v = *(reinterpret_cast<const float4*>(
                           author_h + (size_t)hp_src[e] * 256) + lane);
            ax += v.x * wt; ay += v.y * wt; az += v.z * wt; aw += v.w * wt;
        }
    }
    float4 o = {ax, ay, az, aw};
    *(reinterpret_cast<float4*>(out + (size_t)row * 256) + lane) = o;
}

// ---------------- fallback (round-1 atomic path) ----------------

__global__ __launch_bounds__(256) void edge_scatter_kernel(
    const float* __restrict__ src_h, const int* __restrict__ src_idx,
    const int* __restrict__ dst_idx, const float* __restrict__ w0,
    const float* __restrict__ w1, float* __restrict__ out, int n_edges)
{
    int tid = blockIdx.x * blockDim.x + threadIdx.x;
    int e = tid >> 6;
    if (e >= n_edges) return;
    int lane = tid & 63;
    float w = w0[e];
    if (w1) w *= w1[e];
    const float4 v = *(reinterpret_cast<const float4*>(
                         src_h + (size_t)src_idx[e] * 256) + lane);
    float* dst = out + (size_t)dst_idx[e] * 256 + (size_t)lane * 4;
    unsafeAtomicAdd(dst + 0, v.x * w);
    unsafeAtomicAdd(dst + 1, v.y * w);
    unsafeAtomicAdd(dst + 2, v.z * w);
    unsafeAtomicAdd(dst + 3, v.w * w);
}

extern "C" void kernel_launch(void* const* d_in, const int* in_sizes, int n_in,
                              void* d_out, int out_size, void* d_ws, size_t ws_size,
                              hipStream_t stream)
{
    const float* paper_h  = (const float*)d_in[0];
    const float* author_h = (const float*)d_in[1];
    const int*   wb_src   = (const int*)d_in[2];
    const int*   wb_dst   = (const int*)d_in[3];
    const float* wb_w     = (const float*)d_in[4];
    const int*   pi_src   = (const int*)d_in[5];
    const int*   pi_dst   = (const int*)d_in[6];
    const float* pi_alpha = (const float*)d_in[7];
    const float* pi_w     = (const float*)d_in[8];
    const int*   hp_src   = (const int*)d_in[9];
    const int*   hp_dst   = (const int*)d_in[10];
    const float* hp_feat  = (const float*)d_in[11];
    const float* hp_alpha = (const float*)d_in[12];

    const int D = 256;
    const int n_paper  = in_sizes[0] / D;
    const int n_author = in_sizes[1] / D;
    const int E_wb = in_sizes[2];
    const int E_pi = in_sizes[5];
    const int E_hp = in_sizes[9];
    const int n_venue = out_size / D - n_paper - n_author;

    float* out        = (float*)d_out;
    float* out_paper  = out;
    float* out_author = out + (size_t)n_paper * D;
    float* out_venue  = out_author + (size_t)n_author * D;

    // passthrough: paper_h -> out0
    hipMemcpyAsync(out_paper, paper_h, (size_t)n_paper * D * sizeof(float),
                   hipMemcpyDeviceToDevice, stream);

    // ---- workspace layout (ints) ----
    int* W = (int*)d_ws;
    int* auth_counts = W;
    int* auth_cursor = auth_counts + n_author;
    int* pi_counts   = auth_cursor + n_author;
    int* pi_cursor   = pi_counts + n_venue;
    int* hp_counts   = pi_cursor + n_venue;
    int* hp_cursor   = hp_counts + n_venue;
    int* auth_offs   = hp_cursor + n_venue;        // n_author + 1
    int* pi_offs     = auth_offs + n_author + 1;   // n_venue + 1
    int* hp_offs     = pi_offs + n_venue + 1;      // n_venue + 1
    int* partials    = hp_offs + n_venue + 1;      // 1024
    int* auth_eids   = partials + 1024;            // E_wb
    int* pi_eids     = auth_eids + E_wb;           // E_pi
    int* hp_eids     = pi_eids + E_pi;             // E_hp
    size_t need_bytes = (size_t)((hp_eids + E_hp) - W) * sizeof(int);

    if (ws_size < need_bytes) {
        // fallback: atomic scatter path
        hipMemsetAsync(out_author, 0,
                       ((size_t)n_author + n_venue) * D * sizeof(float), stream);
        auto launch = [&](const float* sh, const int* si, const int* di,
                          const float* w0, const float* w1, float* dst, int E) {
            if (E <= 0) return;
            edge_scatter_kernel<<<(E + 3) / 4, 256, 0, stream>>>(sh, si, di, w0, w1, dst, E);
        };
        launch(paper_h,  wb_src, wb_dst, wb_w,     nullptr,  out_author, E_wb);
        launch(paper_h,  pi_src, pi_dst, pi_alpha, pi_w,     out_venue,  E_pi);
        launch(author_h, hp_src, hp_dst, hp_feat,  hp_alpha, out_venue,  E_hp);
        return;
    }

    // zero counts+cursors (contiguous)
    hipMemsetAsync(W, 0, (size_t)(2 * n_author + 4 * n_venue) * sizeof(int), stream);

    auto build_csr = [&](const int* dst_idx, int E, int n, int* counts, int* cursor,
                         int* offs, int* eids) {
        hist_kernel<<<(E + 255) / 256, 256, 0, stream>>>(dst_idx, E, counts);
        int nb = (n + 255) / 256;
        scan_block_sums<<<nb, 256, 0, stream>>>(counts, n, partials);
        scan_partials_serial<<<1, 64, 0, stream>>>(partials, nb);
        scan_write_offs<<<nb, 256, 0, stream>>>(counts, n, partials, offs);
        fill_csr<<<(E + 255) / 256, 256, 0, stream>>>(dst_idx, E, offs, cursor, eids);
    };

    build_csr(wb_dst, E_wb, n_author, auth_counts, auth_cursor, auth_offs, auth_eids);
    build_csr(pi_dst, E_pi, n_venue,  pi_counts,   pi_cursor,   pi_offs,   pi_eids);
    build_csr(hp_dst, E_hp, n_venue,  hp_counts,   hp_cursor,   hp_offs,   hp_eids);

    // gathers
    gather_author_kernel<<<((size_t)n_author * 64 + 255) / 256, 256, 0, stream>>>(
        paper_h, wb_src, wb_w, auth_offs, auth_eids, out_author, n_author);

    gather_venue_kernel<<<((size_t)n_venue * 64 + 255) / 256, 256, 0, stream>>>(
        paper_h, pi_src, pi_alpha, pi_w, pi_offs, pi_eids,
        author_h, hp_src, hp_feat, hp_alpha, hp_offs, hp_eids,
        out_venue, n_venue);
}

// Round 3
// 889.938 us; speedup vs baseline: 8.7018x; 1.1755x over previous
//
#include <hip/hip_runtime.h>

// PropLayer: 3 weighted segment-sums + passthrough.
// CSR-gather with pre-joined (dst-sorted) src+weight arrays, unrolled gathers,
// and split-row venue gather with atomic combine.
// out layout (floats): [paper N_P*256][author N_A*256][venue N_V*256]

// ---------------- CSR build ----------------

__global__ __launch_bounds__(256) void hist_kernel(const int* __restrict__ dst, int E,
                                                   int* __restrict__ counts) {
    int e = blockIdx.x * blockDim.x + threadIdx.x;
    if (e < E) atomicAdd(&counts[dst[e]], 1);
}

__global__ __launch_bounds__(256) void scan_block_sums(const int* __restrict__ counts, int n,
                                                       int* __restrict__ partials) {
    __shared__ int s[256];
    int i = blockIdx.x * 256 + threadIdx.x;
    s[threadIdx.x] = (i < n) ? counts[i] : 0;
    __syncthreads();
    for (int st = 128; st > 0; st >>= 1) {
        if (threadIdx.x < st) s[threadIdx.x] += s[threadIdx.x + st];
        __syncthreads();
    }
    if (threadIdx.x == 0) partials[blockIdx.x] = s[0];
}

__global__ void scan_partials_serial(int* partials, int m) {
    if (blockIdx.x == 0 && threadIdx.x == 0) {
        int acc = 0;
        for (int i = 0; i < m; ++i) { int v = partials[i]; partials[i] = acc; acc += v; }
    }
}

__global__ __launch_bounds__(256) void scan_write_offs(const int* __restrict__ counts, int n,
                                                       const int* __restrict__ partials,
                                                       int* __restrict__ offs) {
    __shared__ int s[256];
    int i = blockIdx.x * 256 + threadIdx.x;
    int v = (i < n) ? counts[i] : 0;
    s[threadIdx.x] = v;
    __syncthreads();
    for (int st = 1; st < 256; st <<= 1) {
        int t = (threadIdx.x >= st) ? s[threadIdx.x - st] : 0;
        __syncthreads();
        s[threadIdx.x] += t;
        __syncthreads();
    }
    int incl = s[threadIdx.x];
    if (i < n) offs[i] = partials[blockIdx.x] + (incl - v);
    if (i == n - 1) offs[n] = partials[blockIdx.x] + incl;
}

// writes dst-sorted src index + combined weight (w0 * optional w1)
__global__ __launch_bounds__(256) void fill_csr_joined(
    const int* __restrict__ dst, const int* __restrict__ src,
    const float* __restrict__ w0, const float* __restrict__ w1, int E,
    const int* __restrict__ offs, int* __restrict__ cursor,
    int* __restrict__ src_out, float* __restrict__ w_out)
{
    int e = blockIdx.x * blockDim.x + threadIdx.x;
    if (e >= E) return;
    int d = dst[e];
    int pos = offs[d] + atomicAdd(&cursor[d], 1);
    float w = w0[e];
    if (w1) w *= w1[e];
    src_out[pos] = src[e];
    w_out[pos]   = w;
}

// ---------------- gathers ----------------

// one 64-lane wave per author row, unroll x4 for MLP
__global__ __launch_bounds__(256) void gather_author_kernel(
    const float* __restrict__ paper_h,
    const int* __restrict__ offs,
    const int* __restrict__ srcs, const float* __restrict__ ws,
    float* __restrict__ out, int n_rows)
{
    int tid = blockIdx.x * blockDim.x + threadIdx.x;
    int row = tid >> 6, lane = tid & 63;
    if (row >= n_rows) return;
    int beg = offs[row], end = offs[row + 1];
    float ax = 0.f, ay = 0.f, az = 0.f, aw = 0.f;
    int p = beg;
    for (; p + 4 <= end; p += 4) {
        int s0 = srcs[p], s1 = srcs[p+1], s2 = srcs[p+2], s3 = srcs[p+3];
        float w0 = ws[p], w1 = ws[p+1], w2 = ws[p+2], w3 = ws[p+3];
        float4 v0 = *(reinterpret_cast<const float4*>(paper_h + (size_t)s0 * 256) + lane);
        float4 v1 = *(reinterpret_cast<const float4*>(paper_h + (size_t)s1 * 256) + lane);
        float4 v2 = *(reinterpret_cast<const float4*>(paper_h + (size_t)s2 * 256) + lane);
        float4 v3 = *(reinterpret_cast<const float4*>(paper_h + (size_t)s3 * 256) + lane);
        ax += v0.x*w0 + v1.x*w1 + v2.x*w2 + v3.x*w3;
        ay += v0.y*w0 + v1.y*w1 + v2.y*w2 + v3.y*w3;
        az += v0.z*w0 + v1.z*w1 + v2.z*w2 + v3.z*w3;
        aw += v0.w*w0 + v1.w*w1 + v2.w*w2 + v3.w*w3;
    }
    for (; p < end; ++p) {
        int s = srcs[p]; float w = ws[p];
        float4 v = *(reinterpret_cast<const float4*>(paper_h + (size_t)s * 256) + lane);
        ax += v.x*w; ay += v.y*w; az += v.z*w; aw += v.w*w;
    }
    float4 o = {ax, ay, az, aw};
    *(reinterpret_cast<float4*>(out + (size_t)row * 256) + lane) = o;
}

// SPLIT waves per venue row; partials combined with atomics into zeroed out
template<int SPLIT>
__global__ __launch_bounds__(256) void gather_venue_kernel(
    const float* __restrict__ paper_h,
    const int* __restrict__ pi_offs, const int* __restrict__ pi_srcs,
    const float* __restrict__ pi_ws,
    const float* __restrict__ author_h,
    const int* __restrict__ hp_offs, const int* __restrict__ hp_srcs,
    const float* __restrict__ hp_ws,
    float* __restrict__ out, int n_rows)
{
    int tid = blockIdx.x * blockDim.x + threadIdx.x;
    int wid = tid >> 6, lane = tid & 63;
    int row = wid / SPLIT, part = wid % SPLIT;
    if (row >= n_rows) return;
    float ax = 0.f, ay = 0.f, az = 0.f, aw = 0.f;
    bool any = false;

    #pragma unroll
    for (int g = 0; g < 2; ++g) {
        const int*   offs = g ? hp_offs : pi_offs;
        const int*   srcs = g ? hp_srcs : pi_srcs;
        const float* ws   = g ? hp_ws   : pi_ws;
        const float* h    = g ? author_h : paper_h;
        int beg0 = offs[row], end0 = offs[row + 1];
        int total = end0 - beg0;
        int per = (total + SPLIT - 1) / SPLIT;
        int beg = beg0 + part * per;
        int end = min(beg + per, end0);
        if (beg >= end) continue;
        any = true;
        int p = beg;
        for (; p + 4 <= end; p += 4) {
            int s0 = srcs[p], s1 = srcs[p+1], s2 = srcs[p+2], s3 = srcs[p+3];
            float w0 = ws[p], w1 = ws[p+1], w2 = ws[p+2], w3 = ws[p+3];
            float4 v0 = *(reinterpret_cast<const float4*>(h + (size_t)s0 * 256) + lane);
            float4 v1 = *(reinterpret_cast<const float4*>(h + (size_t)s1 * 256) + lane);
            float4 v2 = *(reinterpret_cast<const float4*>(h + (size_t)s2 * 256) + lane);
            float4 v3 = *(reinterpret_cast<const float4*>(h + (size_t)s3 * 256) + lane);
            ax += v0.x*w0 + v1.x*w1 + v2.x*w2 + v3.x*w3;
            ay += v0.y*w0 + v1.y*w1 + v2.y*w2 + v3.y*w3;
            az += v0.z*w0 + v1.z*w1 + v2.z*w2 + v3.z*w3;
            aw += v0.w*w0 + v1.w*w1 + v2.w*w2 + v3.w*w3;
        }
        for (; p < end; ++p) {
            int s = srcs[p]; float w = ws[p];
            float4 v = *(reinterpret_cast<const float4*>(h + (size_t)s * 256) + lane);
            ax += v.x*w; ay += v.y*w; az += v.z*w; aw += v.w*w;
        }
    }
    if (any) {
        float* dst = out + (size_t)row * 256 + (size_t)lane * 4;
        unsafeAtomicAdd(dst + 0, ax);
        unsafeAtomicAdd(dst + 1, ay);
        unsafeAtomicAdd(dst + 2, az);
        unsafeAtomicAdd(dst + 3, aw);
    }
}

// ---------------- fallback (atomic scatter path) ----------------

__global__ __launch_bounds__(256) void edge_scatter_kernel(
    const float* __restrict__ src_h, const int* __restrict__ src_idx,
    const int* __restrict__ dst_idx, const float* __restrict__ w0,
    const float* __restrict__ w1, float* __restrict__ out, int n_edges)
{
    int tid = blockIdx.x * blockDim.x + threadIdx.x;
    int e = tid >> 6;
    if (e >= n_edges) return;
    int lane = tid & 63;
    float w = w0[e];
    if (w1) w *= w1[e];
    const float4 v = *(reinterpret_cast<const float4*>(
                         src_h + (size_t)src_idx[e] * 256) + lane);
    float* dst = out + (size_t)dst_idx[e] * 256 + (size_t)lane * 4;
    unsafeAtomicAdd(dst + 0, v.x * w);
    unsafeAtomicAdd(dst + 1, v.y * w);
    unsafeAtomicAdd(dst + 2, v.z * w);
    unsafeAtomicAdd(dst + 3, v.w * w);
}

extern "C" void kernel_launch(void* const* d_in, const int* in_sizes, int n_in,
                              void* d_out, int out_size, void* d_ws, size_t ws_size,
                              hipStream_t stream)
{
    const float* paper_h  = (const float*)d_in[0];
    const float* author_h = (const float*)d_in[1];
    const int*   wb_src   = (const int*)d_in[2];
    const int*   wb_dst   = (const int*)d_in[3];
    const float* wb_w     = (const float*)d_in[4];
    const int*   pi_src   = (const int*)d_in[5];
    const int*   pi_dst   = (const int*)d_in[6];
    const float* pi_alpha = (const float*)d_in[7];
    const float* pi_w     = (const float*)d_in[8];
    const int*   hp_src   = (const int*)d_in[9];
    const int*   hp_dst   = (const int*)d_in[10];
    const float* hp_feat  = (const float*)d_in[11];
    const float* hp_alpha = (const float*)d_in[12];

    const int D = 256;
    const int n_paper  = in_sizes[0] / D;
    const int n_author = in_sizes[1] / D;
    const int E_wb = in_sizes[2];
    const int E_pi = in_sizes[5];
    const int E_hp = in_sizes[9];
    const int n_venue = out_size / D - n_paper - n_author;

    float* out        = (float*)d_out;
    float* out_paper  = out;
    float* out_author = out + (size_t)n_paper * D;
    float* out_venue  = out_author + (size_t)n_author * D;

    // passthrough: paper_h -> out0
    hipMemcpyAsync(out_paper, paper_h, (size_t)n_paper * D * sizeof(float),
                   hipMemcpyDeviceToDevice, stream);

    // ---- workspace layout ----
    int* W = (int*)d_ws;
    int* auth_counts = W;
    int* auth_cursor = auth_counts + n_author;
    int* pi_counts   = auth_cursor + n_author;
    int* pi_cursor   = pi_counts + n_venue;
    int* hp_counts   = pi_cursor + n_venue;
    int* hp_cursor   = hp_counts + n_venue;
    int* auth_offs   = hp_cursor + n_venue;        // n_author + 1
    int* pi_offs     = auth_offs + n_author + 1;   // n_venue + 1
    int* hp_offs     = pi_offs + n_venue + 1;      // n_venue + 1
    int* partials    = hp_offs + n_venue + 1;      // 1024
    int*   auth_srcs = partials + 1024;            // E_wb
    float* auth_ws   = (float*)(auth_srcs + E_wb); // E_wb
    int*   pi_srcs   = (int*)(auth_ws + E_wb);     // E_pi
    float* pi_ws     = (float*)(pi_srcs + E_pi);   // E_pi
    int*   hp_srcs   = (int*)(pi_ws + E_pi);       // E_hp
    float* hp_ws     = (float*)(hp_srcs + E_hp);   // E_hp
    size_t need_bytes = (size_t)((int*)(hp_ws + E_hp) - W) * sizeof(int);

    if (ws_size < need_bytes) {
        // fallback: atomic scatter path
        hipMemsetAsync(out_author, 0,
                       ((size_t)n_author + n_venue) * D * sizeof(float), stream);
        auto launch = [&](const float* sh, const int* si, const int* di,
                          const float* w0, const float* w1, float* dst, int E) {
            if (E <= 0) return;
            edge_scatter_kernel<<<(E + 3) / 4, 256, 0, stream>>>(sh, si, di, w0, w1, dst, E);
        };
        launch(paper_h,  wb_src, wb_dst, wb_w,     nullptr,  out_author, E_wb);
        launch(paper_h,  pi_src, pi_dst, pi_alpha, pi_w,     out_venue,  E_pi);
        launch(author_h, hp_src, hp_dst, hp_feat,  hp_alpha, out_venue,  E_hp);
        return;
    }

    // zero counts+cursors (contiguous) and the venue accumulator region
    hipMemsetAsync(W, 0, (size_t)(2 * n_author + 4 * n_venue) * sizeof(int), stream);
    hipMemsetAsync(out_venue, 0, (size_t)n_venue * D * sizeof(float), stream);

    auto build_csr = [&](const int* dst_idx, const int* src_idx,
                         const float* w0, const float* w1, int E, int n,
                         int* counts, int* cursor, int* offs,
                         int* srcs, float* ws) {
        hist_kernel<<<(E + 255) / 256, 256, 0, stream>>>(dst_idx, E, counts);
        int nb = (n + 255) / 256;
        scan_block_sums<<<nb, 256, 0, stream>>>(counts, n, partials);
        scan_partials_serial<<<1, 64, 0, stream>>>(partials, nb);
        scan_write_offs<<<nb, 256, 0, stream>>>(counts, n, partials, offs);
        fill_csr_joined<<<(E + 255) / 256, 256, 0, stream>>>(
            dst_idx, src_idx, w0, w1, E, offs, cursor, srcs, ws);
    };

    build_csr(wb_dst, wb_src, wb_w,     nullptr,  E_wb, n_author,
              auth_counts, auth_cursor, auth_offs, auth_srcs, auth_ws);
    build_csr(pi_dst, pi_src, pi_alpha, pi_w,     E_pi, n_venue,
              pi_counts, pi_cursor, pi_offs, pi_srcs, pi_ws);
    build_csr(hp_dst, hp_src, hp_feat,  hp_alpha, E_hp, n_venue,
              hp_counts, hp_cursor, hp_offs, hp_srcs, hp_ws);

    // gathers
    gather_author_kernel<<<((size_t)n_author * 64 + 255) / 256, 256, 0, stream>>>(
        paper_h, auth_offs, auth_srcs, auth_ws, out_author, n_author);

    constexpr int SPLIT = 4;
    gather_venue_kernel<SPLIT><<<((size_t)n_venue * SPLIT * 64 + 255) / 256, 256, 0, stream>>>(
        paper_h, pi_offs, pi_srcs, pi_ws,
        author_h, hp_offs, hp_srcs, hp_ws,
        out_venue, n_venue);
}